// Round 5
// baseline (278.475 us; speedup 1.0000x reference)
//
#include <hip/hip_runtime.h>

// ContextTokenModel — round 14: hoist the x-projection out of the serial loop.
//  kxp0: xg0[t,btile,dir][6 frags] = bias + x_t @ Wx  (f32, bit-identical
//        accumulation order to the old in-loop MFMAs), full occupancy.
//  krec0: per step only 6 h-dependent MFMAs + activations + LDS transposes,
//        xpart loads double-buffered one step ahead.
//  kxp1/k3b: same split for layer 1 (xg1 = bias + y0 @ W, reuses xg buffer).
//  kswz: one-time pre-swizzle of all weight B-frags to per-lane uint4 layout.
// B=8192, T=21, D_in=160, H=32. Output fp32 [B,21,64] (fw|bw).

typedef __attribute__((ext_vector_type(8))) short short8;
typedef __attribute__((ext_vector_type(8))) __bf16 bf16x8;
typedef __attribute__((ext_vector_type(4))) float f32x4;
typedef unsigned short ushort_t;

// ---- bf16 cvt region (ushort offsets from ws+64) ----
#define U_TOKEMB  0             // 5000*128
#define U_TYPEMB  640000        // 5000*32
#define U_HOLE    800000        // 160
#define U_GKFW0   800160        // 192*64
#define U_GBFW0   812448        // 64
#define U_CKFW0   812512        // 192*32
#define U_CBFW0   818656        // 32
#define U_GKBW0   818688
#define U_GBBW0   830976
#define U_CKBW0   831040
#define U_CBBW0   837184
#define U_GKFW1   837216        // 96*64
#define U_GBFW1   843360
#define U_CKFW1   843424        // 96*32
#define U_CBFW1   846496
#define U_GKBW1   846528
#define U_GBBW1   852672
#define U_CKBW1   852736
#define U_CBBW1   855808
// cvt ends at 64 + 855840*2 = 1,711,744 B

#define Y0A_OFF   (4u << 20)    // y0a bf16 A-frags: uint4 [21*512][2][64] = 22,020,096 B
#define TYPF_OFF  (25u << 20)   // type-max bf16 A-frags: uint4 [20*512][64] = 10,485,760 B
#define WF_OFF    (37u << 20)   // swizzled weight B-frags: uint4 [108][64] = 110,592 B
#define XG_OFF    (40u << 20)   // x-projection partials: uint4 [21504][6][64] = 132,120,576 B

#define XG_TSTRIDE ((size_t)512 * 2 * 6 * 64)   // uint4s per t-slice

__device__ __forceinline__ float bf2f(unsigned int u) {
  union { unsigned int i; float f; } v; v.i = u << 16; return v.f;
}
__device__ __forceinline__ unsigned short f2bf(float f) {
  unsigned int u = __float_as_uint(f);
  u += 0x7fffu + ((u >> 16) & 1u);
  return (unsigned short)(u >> 16);
}
__device__ __forceinline__ f32x4 mfma16(short8 a, short8 b, f32x4 c) {
  return __builtin_amdgcn_mfma_f32_16x16x32_bf16(
      __builtin_bit_cast(bf16x8, a), __builtin_bit_cast(bf16x8, b), c, 0, 0, 0);
}
__device__ __forceinline__ float sgm(float x) {
  x = fminf(fmaxf(x, -30.f), 30.f);
  return __fdividef(1.f, 1.f + __expf(-x));
}
__device__ __forceinline__ float tnh(float x) {
  x = fminf(fmaxf(x, -15.f), 15.f);
  float e = __expf(2.f * x);
  return (e - 1.f) * __fdividef(1.f, e + 1.f);
}

// ---------------------------------------------------------------------------
// k0 probes (validated in r8). flags[0]=fp32 floats; flags[1]=byte masks;
// flags[2]=types/mask slots swapped.
// ---------------------------------------------------------------------------
__global__ void k0_detect(const ushort_t* __restrict__ probe_f,
                          const unsigned* __restrict__ probe_m,
                          const unsigned* __restrict__ probe_t,
                          int* __restrict__ flags) {
  const int lane = threadIdx.x;  // 64
  int cnt = 0;
#pragma unroll
  for (int i = 0; i < 4; ++i) {
    unsigned e = ((unsigned)probe_f[lane + i * 64] >> 7) & 0xffu;
    if (e == 0u || (e >= 112u && e <= 134u)) cnt++;
  }
#pragma unroll
  for (int off = 32; off > 0; off >>= 1) cnt += __shfl_down(cnt, off, 64);
  const unsigned v = probe_m[lane];
  const unsigned long long bytelike =
      __ballot((v > 1u) && (v != 0x3F800000u) && ((v & 0xFEFEFEFEu) == 0u));
  const unsigned tv = probe_t[lane];
  const unsigned long long tlooksTypes =
      __ballot(!(tv == 0u || tv == 1u || tv == 0x3F800000u));
  if (lane == 0) {
    flags[0] = (cnt < 205) ? 1 : 0;
    flags[1] = bytelike ? 1 : 0;
    flags[2] = tlooksTypes ? 0 : 1;
  }
}

// ---------------------------------------------------------------------------
// kcvt: normalize all 19 float inputs to bf16 cvt region.
// ---------------------------------------------------------------------------
struct Cvt19 { const void* src[19]; int len[19]; int dst[19]; };

__global__ void kcvt(Cvt19 a, ushort_t* __restrict__ cvt, const int* __restrict__ flags) {
  const int fp32 = flags[0];
  int gid = blockIdx.x * blockDim.x + threadIdx.x;
#pragma unroll 1
  for (int s = 0; s < 19; ++s) {
    if (gid < a.len[s]) {
      cvt[a.dst[s] + gid] = fp32 ? f2bf(((const float*)a.src[s])[gid])
                                 : ((const ushort_t*)a.src[s])[gid];
      return;
    }
    gid -= a.len[s];
  }
}

// ---------------------------------------------------------------------------
// kswz: pre-swizzle all weight B-frags into per-lane uint4 layout.
// L0 dir d: frag f<20: wg[kt=f>>2][tn=f&3]; 20..29: wc; 30..33: wgh; 34..35: wch.
// L1 dir d: f<12: wg[kt=f>>2][tn=f&3]; 12..17: wc.
// wf[(layer? 72 + d*18+f : d*36+f)*64 + lane]
// ---------------------------------------------------------------------------
__global__ void kswz(const ushort_t* __restrict__ cvt, uint4* __restrict__ wf) {
  const int id = blockIdx.x * blockDim.x + threadIdx.x;
  if (id >= 108 * 64) return;
  const int frag = id >> 6, lane = id & 63;
  const int q = lane >> 4, nl = lane & 15;
  const int layer = (frag >= 72) ? 1 : 0;
  const int fr = layer ? frag - 72 : frag;
  const int nper = layer ? 18 : 36;
  const int d = fr / nper;
  const int f = fr - d * nper;
  const ushort_t* gk = layer ? (cvt + (d ? U_GKBW1 : U_GKFW1))
                             : (cvt + (d ? U_GKBW0 : U_GKFW0));
  const ushort_t* ck = layer ? (cvt + (d ? U_CKBW1 : U_CKFW1))
                             : (cvt + (d ? U_CKBW0 : U_CKFW0));
  const ushort_t* src; int row0, colw, coloff;
  if (!layer) {
    if (f < 20)      { src = gk; row0 = (f >> 2) * 32; colw = 64; coloff = (f & 3) * 16; }
    else if (f < 30) { int g = f - 20; src = ck; row0 = (g >> 1) * 32; colw = 32; coloff = (g & 1) * 16; }
    else if (f < 34) { src = gk; row0 = 160; colw = 64; coloff = (f - 30) * 16; }
    else             { src = ck; row0 = 160; colw = 32; coloff = (f - 34) * 16; }
  } else {
    if (f < 12)      { src = gk; row0 = (f >> 2) * 32; colw = 64; coloff = (f & 3) * 16; }
    else             { int g = f - 12; src = ck; row0 = (g >> 1) * 32; colw = 32; coloff = (g & 1) * 16; }
  }
  short8 v;
#pragma unroll
  for (int j = 0; j < 8; ++j)
    v[j] = (short)src[(row0 + q * 8 + j) * colw + coloff + nl];
  wf[frag * 64 + lane] = __builtin_bit_cast(uint4, v);
}

// ---------------------------------------------------------------------------
// ktypmax: masked type-embedding max, fully parallel. Same bits as in-loop.
// ---------------------------------------------------------------------------
__global__ __launch_bounds__(256) void ktypmax(
    const void* __restrict__ slot_tb, const void* __restrict__ slot_mb,
    const void* __restrict__ slot_ta, const void* __restrict__ slot_ma,
    const ushort_t* __restrict__ cvt, uint4* __restrict__ typf,
    const int* __restrict__ flags) {
  const int wv = threadIdx.x >> 6;
  const int lane = threadIdx.x & 63;
  const int q = lane >> 4, nl = lane & 15;
  const int job = blockIdx.x * 4 + wv;           // [0, 10240)
  const int st = job >> 9;                       // 0..19  (side*10+ts)
  const int btile = job & 511;
  const int side = (st >= 10) ? 1 : 0;
  const int ts = st - side * 10;
  const int b = btile * 16 + nl;
  const int sw = flags[2];
  const int bytem = flags[1];
  const int* tys = side ? (const int*)(sw ? slot_ma : slot_ta)
                        : (const int*)(sw ? slot_mb : slot_tb);
  const void* msk = side ? (sw ? slot_ta : slot_ma)
                         : (sw ? slot_tb : slot_mb);
  const int base = (b * 10 + ts) * 10;
  float mx[8];
#pragma unroll
  for (int j = 0; j < 8; ++j) mx[j] = -1e30f;
#pragma unroll
  for (int nt = 0; nt < 10; ++nt) {
    const int ty = tys[base + nt];
    const bool mv = bytem ? (((const unsigned char*)msk)[base + nt] != 0)
                          : (((const unsigned*)msk)[base + nt] != 0u);
    const float pen = mv ? 0.f : -1000.f;
    uint4 e = *reinterpret_cast<const uint4*>(cvt + U_TYPEMB + (size_t)ty * 32 + q * 8);
    const unsigned w[4] = {e.x, e.y, e.z, e.w};
#pragma unroll
    for (int j2 = 0; j2 < 4; ++j2) {
      mx[2 * j2]     = fmaxf(mx[2 * j2],     bf2f(w[j2] & 0xffffu) + pen);
      mx[2 * j2 + 1] = fmaxf(mx[2 * j2 + 1], bf2f(w[j2] >> 16) + pen);
    }
  }
  short8 v;
#pragma unroll
  for (int j = 0; j < 8; ++j) v[j] = (short)f2bf(mx[j]);
  typf[(size_t)job * 64 + lane] = __builtin_bit_cast(uint4, v);
}

// ---------------------------------------------------------------------------
// x-gather: token-embedding frags + one precomputed typf load.
// ---------------------------------------------------------------------------
__device__ __forceinline__ void gatherX(
    int t, int btile, int lane,
    const int* __restrict__ tok_b, const int* __restrict__ tok_a,
    const ushort_t* __restrict__ cvt, const uint4* __restrict__ typf,
    short8 af[5]) {
  const int q = lane >> 4, nl = lane & 15;
  if (t == 10) {
#pragma unroll
    for (int kt = 0; kt < 5; ++kt)
      af[kt] = __builtin_bit_cast(short8,
          *reinterpret_cast<const uint4*>(cvt + U_HOLE + kt * 32 + q * 8));
    return;
  }
  const int ts = (t < 10) ? t : t - 11;
  const int side = (t < 10) ? 0 : 1;
  const int b = btile * 16 + nl;
  const int tok = (side ? tok_a : tok_b)[b * 10 + ts];
#pragma unroll
  for (int kt = 0; kt < 4; ++kt)
    af[kt] = __builtin_bit_cast(short8,
        *reinterpret_cast<const uint4*>(cvt + U_TOKEMB + (size_t)tok * 128 + kt * 32 + q * 8));
  af[4] = __builtin_bit_cast(short8,
      typf[((size_t)(side * 10 + ts) * 512 + btile) * 64 + lane]);
}

// ---------------------------------------------------------------------------
// kxp0: layer-0 x-projection, fully parallel over (t,btile,dir) = 21504 jobs.
// xg[job][tn<4]=gate pre-act (bias + 5 x-MFMAs, same order as old in-loop);
// xg[job][4+tn]=cand pre-act. f32 -> bit-identical when krec0 adds the h MFMA.
// ---------------------------------------------------------------------------
__global__ __launch_bounds__(256) void kxp0(
    const int* __restrict__ tok_b, const int* __restrict__ tok_a,
    const ushort_t* __restrict__ cvt, const uint4* __restrict__ typf,
    const uint4* __restrict__ wf, uint4* __restrict__ xg) {
  const int wv = threadIdx.x >> 6;
  const int lane = threadIdx.x & 63;
  const int nl = lane & 15;
  const int job = blockIdx.x * 4 + wv;           // [0, 21504)
  const int dir = job & 1;
  const int r2 = job >> 1;
  const int t = r2 >> 9, btile = r2 & 511;

  short8 af[5];
  gatherX(t, btile, lane, tok_b, tok_a, cvt, typf, af);

  const uint4* wfL0 = wf + dir * 36 * 64;
  const ushort_t* gb = cvt + (dir ? U_GBBW0 : U_GBFW0);
  const ushort_t* cb = cvt + (dir ? U_CBBW0 : U_CBFW0);
  uint4* xo = xg + (size_t)job * 6 * 64;

#pragma unroll
  for (int tn = 0; tn < 4; ++tn) {
    const float b = bf2f((unsigned)gb[tn * 16 + nl]);
    f32x4 acc = {b, b, b, b};
#pragma unroll
    for (int kt = 0; kt < 5; ++kt)
      acc = mfma16(af[kt], __builtin_bit_cast(short8, wfL0[(kt * 4 + tn) * 64 + lane]), acc);
    xo[tn * 64 + lane] = __builtin_bit_cast(uint4, acc);
  }
#pragma unroll
  for (int tn = 0; tn < 2; ++tn) {
    const float b = bf2f((unsigned)cb[tn * 16 + nl]);
    f32x4 acc = {b, b, b, b};
#pragma unroll
    for (int kt = 0; kt < 5; ++kt)
      acc = mfma16(af[kt], __builtin_bit_cast(short8, wfL0[(20 + kt * 2 + tn) * 64 + lane]), acc);
    xo[(4 + tn) * 64 + lane] = __builtin_bit_cast(uint4, acc);
  }
}

// ---------------------------------------------------------------------------
// krec0: layer-0 recurrence, h-dependent work only (6 MFMAs/step).
// 1024 wave-jobs, no barriers, xpart double-buffered one step ahead.
// ---------------------------------------------------------------------------
__global__ __launch_bounds__(256) void krec0(
    const ushort_t* __restrict__ cvt, const uint4* __restrict__ wf,
    const uint4* __restrict__ xg, uint4* __restrict__ y0a) {
  __shared__ __align__(16) ushort_t hbuf[4][2][16 * 40];
  const int wv = threadIdx.x >> 6;
  const int lane = threadIdx.x & 63;
  const int q = lane >> 4, nl = lane & 15;
  const int job = blockIdx.x * 4 + wv;
  const int dir = job & 1, btile = job >> 1;

  const uint4* wfL0 = wf + dir * 36 * 64;
  short8 wgh[4], wch[2];
#pragma unroll
  for (int tn = 0; tn < 4; ++tn)
    wgh[tn] = __builtin_bit_cast(short8, wfL0[(30 + tn) * 64 + lane]);
#pragma unroll
  for (int tn = 0; tn < 2; ++tn)
    wch[tn] = __builtin_bit_cast(short8, wfL0[(34 + tn) * 64 + lane]);

  f32x4 hc0 = {0.f, 0.f, 0.f, 0.f}, hc1 = {0.f, 0.f, 0.f, 0.f};
  short8 hA = {0, 0, 0, 0, 0, 0, 0, 0};
  ushort_t* hb0 = hbuf[wv][0];
  ushort_t* hb1 = hbuf[wv][1];

  const int t0 = dir ? 20 : 0;
  const uint4* xp = xg + ((size_t)(t0 * 512 + btile) * 2 + dir) * 6 * 64 + lane;
  const long step = dir ? -(long)XG_TSTRIDE : (long)XG_TSTRIDE;

  f32x4 cur[6], nxt[6];
#pragma unroll
  for (int tn = 0; tn < 6; ++tn) cur[tn] = __builtin_bit_cast(f32x4, xp[tn * 64]);

  for (int s = 0; s < 21; ++s) {
    const int t = dir ? 20 - s : s;
    if (s < 20) {
      const uint4* xn = xp + step;
#pragma unroll
      for (int tn = 0; tn < 6; ++tn) nxt[tn] = __builtin_bit_cast(f32x4, xn[tn * 64]);
      xp = xn;
    }

    // gates: pre-act = xpart + h MFMA
    f32x4 ru[4];
#pragma unroll
    for (int tn = 0; tn < 4; ++tn) ru[tn] = mfma16(hA, wgh[tn], cur[tn]);
#pragma unroll
    for (int tn = 0; tn < 4; ++tn)
#pragma unroll
      for (int r = 0; r < 4; ++r) ru[tn][r] = sgm(ru[tn][r]);

    // r*h -> A-layout via per-wave LDS
#pragma unroll
    for (int r = 0; r < 4; ++r) {
      hb0[(q * 4 + r) * 40 + nl]      = f2bf(ru[0][r] * hc0[r]);
      hb0[(q * 4 + r) * 40 + 16 + nl] = f2bf(ru[1][r] * hc1[r]);
    }
    short8 rhA = *reinterpret_cast<const short8*>(hb0 + nl * 40 + q * 8);

    // candidate
    f32x4 cc0 = mfma16(rhA, wch[0], cur[4]);
    f32x4 cc1 = mfma16(rhA, wch[1], cur[5]);
#pragma unroll
    for (int r = 0; r < 4; ++r) {
      const float c0 = tnh(cc0[r]), c1 = tnh(cc1[r]);
      const float u0 = ru[2][r], u1 = ru[3][r];
      hc0[r] = u0 * hc0[r] + (1.f - u0) * c0;
      hc1[r] = u1 * hc1[r] + (1.f - u1) * c1;
    }

    // h' -> A-layout
#pragma unroll
    for (int r = 0; r < 4; ++r) {
      hb1[(q * 4 + r) * 40 + nl]      = f2bf(hc0[r]);
      hb1[(q * 4 + r) * 40 + 16 + nl] = f2bf(hc1[r]);
    }
    hA = *reinterpret_cast<const short8*>(hb1 + nl * 40 + q * 8);
    y0a[((size_t)(t * 512 + btile) * 2 + dir) * 64 + lane] = __builtin_bit_cast(uint4, hA);

    if (s < 20) {
#pragma unroll
      for (int tn = 0; tn < 6; ++tn) cur[tn] = nxt[tn];
    }
  }
}

// ---------------------------------------------------------------------------
// kxp1: layer-1 x-projection: xg[job] = bias + ya0@W + ya1@W (same order as
// old k3b prefix). Runs after krec0; reuses the xg buffer.
// ---------------------------------------------------------------------------
__global__ __launch_bounds__(256) void kxp1(
    const ushort_t* __restrict__ cvt, const uint4* __restrict__ y0a,
    const uint4* __restrict__ wf, uint4* __restrict__ xg) {
  const int wv = threadIdx.x >> 6;
  const int lane = threadIdx.x & 63;
  const int nl = lane & 15;
  const int job = blockIdx.x * 4 + wv;           // [0, 21504)
  const int dir = job & 1;
  const int r2 = job >> 1;
  const int t = r2 >> 9, btile = r2 & 511;

  const short8 ya0 = __builtin_bit_cast(short8, y0a[((size_t)(t * 512 + btile) * 2 + 0) * 64 + lane]);
  const short8 ya1 = __builtin_bit_cast(short8, y0a[((size_t)(t * 512 + btile) * 2 + 1) * 64 + lane]);

  const uint4* wfL1 = wf + (72 + dir * 18) * 64;
  const ushort_t* gb = cvt + (dir ? U_GBBW1 : U_GBFW1);
  const ushort_t* cb = cvt + (dir ? U_CBBW1 : U_CBFW1);
  uint4* xo = xg + (size_t)job * 6 * 64;

#pragma unroll
  for (int tn = 0; tn < 4; ++tn) {
    const float b = bf2f((unsigned)gb[tn * 16 + nl]);
    f32x4 acc = {b, b, b, b};
    acc = mfma16(ya0, __builtin_bit_cast(short8, wfL1[tn * 64 + lane]), acc);
    acc = mfma16(ya1, __builtin_bit_cast(short8, wfL1[(4 + tn) * 64 + lane]), acc);
    xo[tn * 64 + lane] = __builtin_bit_cast(uint4, acc);
  }
#pragma unroll
  for (int tn = 0; tn < 2; ++tn) {
    const float b = bf2f((unsigned)cb[tn * 16 + nl]);
    f32x4 acc = {b, b, b, b};
    acc = mfma16(ya0, __builtin_bit_cast(short8, wfL1[(12 + tn) * 64 + lane]), acc);
    acc = mfma16(ya1, __builtin_bit_cast(short8, wfL1[(14 + tn) * 64 + lane]), acc);
    xo[(4 + tn) * 64 + lane] = __builtin_bit_cast(uint4, acc);
  }
}

// ---------------------------------------------------------------------------
// k3b: layer-1 recurrence, h-dependent work only; FP32 output [b][21][64].
// ---------------------------------------------------------------------------
__global__ __launch_bounds__(256) void k3b(
    const uint4* __restrict__ wf, const uint4* __restrict__ xg,
    float* __restrict__ out) {
  __shared__ __align__(16) ushort_t hbuf[4][2][16 * 40];
  const int wv = threadIdx.x >> 6;
  const int lane = threadIdx.x & 63;
  const int q = lane >> 4, nl = lane & 15;
  const int job = blockIdx.x * 4 + wv;
  const int dir = job & 1, btile = job >> 1;

  const uint4* wfL1 = wf + (72 + dir * 18) * 64;
  short8 wgh[4], wch[2];
#pragma unroll
  for (int tn = 0; tn < 4; ++tn)
    wgh[tn] = __builtin_bit_cast(short8, wfL1[(8 + tn) * 64 + lane]);
#pragma unroll
  for (int tn = 0; tn < 2; ++tn)
    wch[tn] = __builtin_bit_cast(short8, wfL1[(16 + tn) * 64 + lane]);

  f32x4 hc0 = {0.f, 0.f, 0.f, 0.f}, hc1 = {0.f, 0.f, 0.f, 0.f};
  short8 hA = {0, 0, 0, 0, 0, 0, 0, 0};
  ushort_t* hb0 = hbuf[wv][0];
  ushort_t* hb1 = hbuf[wv][1];

  const int t0 = dir ? 20 : 0;
  const uint4* xp = xg + ((size_t)(t0 * 512 + btile) * 2 + dir) * 6 * 64 + lane;
  const long step = dir ? -(long)XG_TSTRIDE : (long)XG_TSTRIDE;

  f32x4 cur[6], nxt[6];
#pragma unroll
  for (int tn = 0; tn < 6; ++tn) cur[tn] = __builtin_bit_cast(f32x4, xp[tn * 64]);

  for (int s = 0; s < 21; ++s) {
    const int t = dir ? 20 - s : s;
    if (s < 20) {
      const uint4* xn = xp + step;
#pragma unroll
      for (int tn = 0; tn < 6; ++tn) nxt[tn] = __builtin_bit_cast(f32x4, xn[tn * 64]);
      xp = xn;
    }

    f32x4 ru[4];
#pragma unroll
    for (int tn = 0; tn < 4; ++tn) ru[tn] = mfma16(hA, wgh[tn], cur[tn]);
#pragma unroll
    for (int tn = 0; tn < 4; ++tn)
#pragma unroll
      for (int r = 0; r < 4; ++r) ru[tn][r] = sgm(ru[tn][r]);

#pragma unroll
    for (int r = 0; r < 4; ++r) {
      hb0[(q * 4 + r) * 40 + nl]      = f2bf(ru[0][r] * hc0[r]);
      hb0[(q * 4 + r) * 40 + 16 + nl] = f2bf(ru[1][r] * hc1[r]);
    }
    short8 rhA = *reinterpret_cast<const short8*>(hb0 + nl * 40 + q * 8);

    f32x4 cc0 = mfma16(rhA, wch[0], cur[4]);
    f32x4 cc1 = mfma16(rhA, wch[1], cur[5]);
#pragma unroll
    for (int r = 0; r < 4; ++r) {
      const float c0 = tnh(cc0[r]), c1 = tnh(cc1[r]);
      const float u0 = ru[2][r], u1 = ru[3][r];
      hc0[r] = u0 * hc0[r] + (1.f - u0) * c0;
      hc1[r] = u1 * hc1[r] + (1.f - u1) * c1;
    }

#pragma unroll
    for (int r = 0; r < 4; ++r) {
      hb1[(q * 4 + r) * 40 + nl]      = f2bf(hc0[r]);
      hb1[(q * 4 + r) * 40 + 16 + nl] = f2bf(hc1[r]);
    }
    hA = *reinterpret_cast<const short8*>(hb1 + nl * 40 + q * 8);

    // FP32 output: lane holds h'[m=q*4+r][ch nl and 16+nl] for this dir
#pragma unroll
    for (int r = 0; r < 4; ++r) {
      const size_t o = ((size_t)(btile * 16 + q * 4 + r) * 21 + t) * 64 + dir * 32 + nl;
      out[o]      = hc0[r];
      out[o + 16] = hc1[r];
    }

    if (s < 20) {
#pragma unroll
      for (int tn = 0; tn < 6; ++tn) cur[tn] = nxt[tn];
    }
  }
}

// ---------------------------------------------------------------------------
extern "C" void kernel_launch(void* const* d_in, const int* in_sizes, int n_in,
                              void* d_out, int out_size, void* d_ws, size_t ws_size,
                              hipStream_t stream)
{
  const int* tok_b = (const int*)d_in[0];
  const void* slot_tb = d_in[1];
  const void* slot_mb = d_in[2];
  const int* tok_a = (const int*)d_in[3];
  const void* slot_ta = d_in[4];
  const void* slot_ma = d_in[5];

  int* flags = (int*)d_ws;
  ushort_t* cvt = (ushort_t*)((char*)d_ws + 64);
  uint4* y0a = (uint4*)((char*)d_ws + Y0A_OFF);
  uint4* typf = (uint4*)((char*)d_ws + TYPF_OFF);
  uint4* wf  = (uint4*)((char*)d_ws + WF_OFF);
  uint4* xg  = (uint4*)((char*)d_ws + XG_OFF);

  k0_detect<<<dim3(1), dim3(64), 0, stream>>>(
      (const ushort_t*)d_in[6], (const unsigned*)slot_mb, (const unsigned*)slot_tb,
      flags);

  static const int slen[19] = {640000, 160000, 160,
                               12288, 64, 6144, 32, 12288, 64, 6144, 32,
                               6144, 64, 3072, 32, 6144, 64, 3072, 32};
  static const int sdst[19] = {U_TOKEMB, U_TYPEMB, U_HOLE,
                               U_GKFW0, U_GBFW0, U_CKFW0, U_CBFW0,
                               U_GKBW0, U_GBBW0, U_CKBW0, U_CBBW0,
                               U_GKFW1, U_GBFW1, U_CKFW1, U_CBFW1,
                               U_GKBW1, U_GBBW1, U_CKBW1, U_CBBW1};
  Cvt19 a;
  int tot = 0;
  for (int i = 0; i < 19; ++i) {
    a.src[i] = d_in[6 + i]; a.len[i] = slen[i]; a.dst[i] = sdst[i]; tot += slen[i];
  }
  kcvt<<<dim3((tot + 255) / 256), dim3(256), 0, stream>>>(a, cvt, flags);

  kswz<<<dim3(27), dim3(256), 0, stream>>>(cvt, wf);

  ktypmax<<<dim3(2560), dim3(256), 0, stream>>>(
      slot_tb, slot_mb, slot_ta, slot_ma, cvt, typf, flags);

  kxp0<<<dim3(5376), dim3(256), 0, stream>>>(tok_b, tok_a, cvt, typf, wf, xg);

  krec0<<<dim3(256), dim3(256), 0, stream>>>(cvt, wf, xg, y0a);

  kxp1<<<dim3(5376), dim3(256), 0, stream>>>(cvt, y0a, wf, xg);

  k3b<<<dim3(256), dim3(256), 0, stream>>>(wf, xg, (float*)d_out);
}

// Round 6
// 220.422 us; speedup vs baseline: 1.2634x; 1.2634x over previous
//
#include <hip/hip_runtime.h>

// ContextTokenModel — round 15: project the VOCABULARY, not the batch.
//  kproj: PROJ[dir][5001][96] = bias + tok_emb @ Wx[0:128] via the SAME MFMAs
//         (bias, kt=0..3 order) -> 3.85 MB, L2/L3-resident. Replaces kxp0's
//         132 MB f32 round-trip (which was write-BW-bound at 44 µs).
//  krec0: per step: 24 f32 PROJ gathers (depth-2 tid pipeline) + 6 typemax
//         MFMAs (kt=4, pipelined off critical path) + 6 h-MFMAs + acts.
//         Accumulation order bias,kt0..4,h preserved -> bit-identical.
//  k3b:   in-loop y0a reads again (no kxp1); 16 y-MFMAs software-pipelined
//         to the previous step (order bias,ya0,ya1,hA preserved).
// B=8192, T=21, D_in=160, H=32. Output fp32 [B,21,64] (fw|bw).

typedef __attribute__((ext_vector_type(8))) short short8;
typedef __attribute__((ext_vector_type(8))) __bf16 bf16x8;
typedef __attribute__((ext_vector_type(4))) float f32x4;
typedef unsigned short ushort_t;

// ---- bf16 cvt region (ushort offsets from ws+64) ----
#define U_TOKEMB  0             // 5000*128
#define U_TYPEMB  640000        // 5000*32
#define U_HOLE    800000        // 160
#define U_GKFW0   800160        // 192*64
#define U_GBFW0   812448        // 64
#define U_CKFW0   812512        // 192*32
#define U_CBFW0   818656        // 32
#define U_GKBW0   818688
#define U_GBBW0   830976
#define U_CKBW0   831040
#define U_CBBW0   837184
#define U_GKFW1   837216        // 96*64
#define U_GBFW1   843360
#define U_CKFW1   843424        // 96*32
#define U_CBFW1   846496
#define U_GKBW1   846528
#define U_GBBW1   852672
#define U_CKBW1   852736
#define U_CBBW1   855808
// cvt ends at 64 + 855840*2 = 1,711,744 B

#define Y0A_OFF   (4u << 20)    // y0a bf16 A-frags: uint4 [21*512][2][64] = 22,020,096 B
#define TYPF_OFF  (25u << 20)   // type-max bf16 A-frags: uint4 [20*512][64] = 10,485,760 B
#define WF_OFF    (37u << 20)   // swizzled weight B-frags: uint4 [108][64] = 110,592 B
#define PROJ_OFF  (40u << 20)   // token projections: f32 [2][5008][6][16] = 3,846,144 B

__device__ __forceinline__ float bf2f(unsigned int u) {
  union { unsigned int i; float f; } v; v.i = u << 16; return v.f;
}
__device__ __forceinline__ unsigned short f2bf(float f) {
  unsigned int u = __float_as_uint(f);
  u += 0x7fffu + ((u >> 16) & 1u);
  return (unsigned short)(u >> 16);
}
__device__ __forceinline__ f32x4 mfma16(short8 a, short8 b, f32x4 c) {
  return __builtin_amdgcn_mfma_f32_16x16x32_bf16(
      __builtin_bit_cast(bf16x8, a), __builtin_bit_cast(bf16x8, b), c, 0, 0, 0);
}
__device__ __forceinline__ float sgm(float x) {
  x = fminf(fmaxf(x, -30.f), 30.f);
  return __fdividef(1.f, 1.f + __expf(-x));
}
__device__ __forceinline__ float tnh(float x) {
  x = fminf(fmaxf(x, -15.f), 15.f);
  float e = __expf(2.f * x);
  return (e - 1.f) * __fdividef(1.f, e + 1.f);
}

// ---------------------------------------------------------------------------
// k0 probes (validated in r8). flags[0]=fp32 floats; flags[1]=byte masks;
// flags[2]=types/mask slots swapped.
// ---------------------------------------------------------------------------
__global__ void k0_detect(const ushort_t* __restrict__ probe_f,
                          const unsigned* __restrict__ probe_m,
                          const unsigned* __restrict__ probe_t,
                          int* __restrict__ flags) {
  const int lane = threadIdx.x;  // 64
  int cnt = 0;
#pragma unroll
  for (int i = 0; i < 4; ++i) {
    unsigned e = ((unsigned)probe_f[lane + i * 64] >> 7) & 0xffu;
    if (e == 0u || (e >= 112u && e <= 134u)) cnt++;
  }
#pragma unroll
  for (int off = 32; off > 0; off >>= 1) cnt += __shfl_down(cnt, off, 64);
  const unsigned v = probe_m[lane];
  const unsigned long long bytelike =
      __ballot((v > 1u) && (v != 0x3F800000u) && ((v & 0xFEFEFEFEu) == 0u));
  const unsigned tv = probe_t[lane];
  const unsigned long long tlooksTypes =
      __ballot(!(tv == 0u || tv == 1u || tv == 0x3F800000u));
  if (lane == 0) {
    flags[0] = (cnt < 205) ? 1 : 0;
    flags[1] = bytelike ? 1 : 0;
    flags[2] = tlooksTypes ? 0 : 1;
  }
}

// ---------------------------------------------------------------------------
// kcvt: normalize all 19 float inputs to bf16 cvt region.
// ---------------------------------------------------------------------------
struct Cvt19 { const void* src[19]; int len[19]; int dst[19]; };

__global__ void kcvt(Cvt19 a, ushort_t* __restrict__ cvt, const int* __restrict__ flags) {
  const int fp32 = flags[0];
  int gid = blockIdx.x * blockDim.x + threadIdx.x;
#pragma unroll 1
  for (int s = 0; s < 19; ++s) {
    if (gid < a.len[s]) {
      cvt[a.dst[s] + gid] = fp32 ? f2bf(((const float*)a.src[s])[gid])
                                 : ((const ushort_t*)a.src[s])[gid];
      return;
    }
    gid -= a.len[s];
  }
}

// ---------------------------------------------------------------------------
// kswz: pre-swizzle all weight B-frags into per-lane uint4 layout (validated r14).
// L0 dir d: f<20: wg[kt=f>>2][tn=f&3]; 20..29: wc[kt=(f-20)>>1][tn]; 30..33: wgh;
// 34..35: wch.  L1: f<12: wg; 12..17: wc.  wf[(layer?72+d*18+f : d*36+f)*64+lane]
// ---------------------------------------------------------------------------
__global__ void kswz(const ushort_t* __restrict__ cvt, uint4* __restrict__ wf) {
  const int id = blockIdx.x * blockDim.x + threadIdx.x;
  if (id >= 108 * 64) return;
  const int frag = id >> 6, lane = id & 63;
  const int q = lane >> 4, nl = lane & 15;
  const int layer = (frag >= 72) ? 1 : 0;
  const int fr = layer ? frag - 72 : frag;
  const int nper = layer ? 18 : 36;
  const int d = fr / nper;
  const int f = fr - d * nper;
  const ushort_t* gk = layer ? (cvt + (d ? U_GKBW1 : U_GKFW1))
                             : (cvt + (d ? U_GKBW0 : U_GKFW0));
  const ushort_t* ck = layer ? (cvt + (d ? U_CKBW1 : U_CKFW1))
                             : (cvt + (d ? U_CKBW0 : U_CKFW0));
  const ushort_t* src; int row0, colw, coloff;
  if (!layer) {
    if (f < 20)      { src = gk; row0 = (f >> 2) * 32; colw = 64; coloff = (f & 3) * 16; }
    else if (f < 30) { int g = f - 20; src = ck; row0 = (g >> 1) * 32; colw = 32; coloff = (g & 1) * 16; }
    else if (f < 34) { src = gk; row0 = 160; colw = 64; coloff = (f - 30) * 16; }
    else             { src = ck; row0 = 160; colw = 32; coloff = (f - 34) * 16; }
  } else {
    if (f < 12)      { src = gk; row0 = (f >> 2) * 32; colw = 64; coloff = (f & 3) * 16; }
    else             { int g = f - 12; src = ck; row0 = (g >> 1) * 32; colw = 32; coloff = (g & 1) * 16; }
  }
  short8 v;
#pragma unroll
  for (int j = 0; j < 8; ++j)
    v[j] = (short)src[(row0 + q * 8 + j) * colw + coloff + nl];
  wf[frag * 64 + lane] = __builtin_bit_cast(uint4, v);
}

// ---------------------------------------------------------------------------
// ktypmax: masked type-embedding max, fully parallel (validated r11/r12).
// ---------------------------------------------------------------------------
__global__ __launch_bounds__(256) void ktypmax(
    const void* __restrict__ slot_tb, const void* __restrict__ slot_mb,
    const void* __restrict__ slot_ta, const void* __restrict__ slot_ma,
    const ushort_t* __restrict__ cvt, uint4* __restrict__ typf,
    const int* __restrict__ flags) {
  const int wv = threadIdx.x >> 6;
  const int lane = threadIdx.x & 63;
  const int q = lane >> 4, nl = lane & 15;
  const int job = blockIdx.x * 4 + wv;           // [0, 10240)
  const int st = job >> 9;                       // 0..19  (side*10+ts)
  const int btile = job & 511;
  const int side = (st >= 10) ? 1 : 0;
  const int ts = st - side * 10;
  const int b = btile * 16 + nl;
  const int sw = flags[2];
  const int bytem = flags[1];
  const int* tys = side ? (const int*)(sw ? slot_ma : slot_ta)
                        : (const int*)(sw ? slot_mb : slot_tb);
  const void* msk = side ? (sw ? slot_ta : slot_ma)
                         : (sw ? slot_tb : slot_mb);
  const int base = (b * 10 + ts) * 10;
  float mx[8];
#pragma unroll
  for (int j = 0; j < 8; ++j) mx[j] = -1e30f;
#pragma unroll
  for (int nt = 0; nt < 10; ++nt) {
    const int ty = tys[base + nt];
    const bool mv = bytem ? (((const unsigned char*)msk)[base + nt] != 0)
                          : (((const unsigned*)msk)[base + nt] != 0u);
    const float pen = mv ? 0.f : -1000.f;
    uint4 e = *reinterpret_cast<const uint4*>(cvt + U_TYPEMB + (size_t)ty * 32 + q * 8);
    const unsigned w[4] = {e.x, e.y, e.z, e.w};
#pragma unroll
    for (int j2 = 0; j2 < 4; ++j2) {
      mx[2 * j2]     = fmaxf(mx[2 * j2],     bf2f(w[j2] & 0xffffu) + pen);
      mx[2 * j2 + 1] = fmaxf(mx[2 * j2 + 1], bf2f(w[j2] >> 16) + pen);
    }
  }
  short8 v;
#pragma unroll
  for (int j = 0; j < 8; ++j) v[j] = (short)f2bf(mx[j]);
  typf[(size_t)job * 64 + lane] = __builtin_bit_cast(uint4, v);
}

// ---------------------------------------------------------------------------
// kproj: token-vocabulary projection. 626 wave-jobs (313 token-tiles x 2 dirs).
// proj[dir][v][g][c] = bias + emb_v @ Wx[kt=0..3]  (g<4: gates, g>=4: cand).
// Same MFMA sequence as the old in-loop prefix -> bit-identical partials.
// Row 5000 = hole vector (token part); rows 5001..5007 dummy (never read).
// ---------------------------------------------------------------------------
__global__ __launch_bounds__(256) void kproj(
    const ushort_t* __restrict__ cvt, const uint4* __restrict__ wf,
    float* __restrict__ proj) {
  const int wv = threadIdx.x >> 6;
  const int lane = threadIdx.x & 63;
  const int q = lane >> 4, nl = lane & 15;
  const int job = blockIdx.x * 4 + wv;
  if (job >= 626) return;
  const int dir = job & 1, tile = job >> 1;      // tile 0..312
  const int v = tile * 16 + nl;
  const ushort_t* src = (v < 5000) ? (cvt + U_TOKEMB + (size_t)v * 128)
                      : (v == 5000) ? (cvt + U_HOLE)
                                    : (cvt + U_TOKEMB);
  short8 af[4];
#pragma unroll
  for (int kt = 0; kt < 4; ++kt)
    af[kt] = __builtin_bit_cast(short8,
        *reinterpret_cast<const uint4*>(src + kt * 32 + q * 8));

  const uint4* wfL0 = wf + dir * 36 * 64;
  const ushort_t* gb = cvt + (dir ? U_GBBW0 : U_GBFW0);
  const ushort_t* cb = cvt + (dir ? U_CBBW0 : U_CBFW0);
  float* po = proj + (size_t)dir * 5008 * 96;

#pragma unroll
  for (int tn = 0; tn < 4; ++tn) {
    const float b = bf2f((unsigned)gb[tn * 16 + nl]);
    f32x4 acc = {b, b, b, b};
#pragma unroll
    for (int kt = 0; kt < 4; ++kt)
      acc = mfma16(af[kt], __builtin_bit_cast(short8, wfL0[(kt * 4 + tn) * 64 + lane]), acc);
#pragma unroll
    for (int r = 0; r < 4; ++r)
      po[((size_t)(tile * 16 + q * 4 + r) * 6 + tn) * 16 + nl] = acc[r];
  }
#pragma unroll
  for (int tn = 0; tn < 2; ++tn) {
    const float b = bf2f((unsigned)cb[tn * 16 + nl]);
    f32x4 acc = {b, b, b, b};
#pragma unroll
    for (int kt = 0; kt < 4; ++kt)
      acc = mfma16(af[kt], __builtin_bit_cast(short8, wfL0[(20 + kt * 2 + tn) * 64 + lane]), acc);
#pragma unroll
    for (int r = 0; r < 4; ++r)
      po[((size_t)(tile * 16 + q * 4 + r) * 6 + (4 + tn)) * 16 + nl] = acc[r];
  }
}

// ---------------------------------------------------------------------------
// krec0: layer-0 recurrence. Per step: 24 f32 PROJ gathers (depth-2 tid
// pipeline) + 6 typemax MFMAs (pipelined) + 6 h-MFMAs + activations.
// 1024 wave-jobs, no barriers. Writes y0a bf16 A-frags.
// ---------------------------------------------------------------------------
__global__ __launch_bounds__(256, 1) void krec0(
    const int* __restrict__ tok_b, const int* __restrict__ tok_a,
    const ushort_t* __restrict__ cvt, const uint4* __restrict__ wf,
    const uint4* __restrict__ typf, const float* __restrict__ proj,
    uint4* __restrict__ y0a) {
  __shared__ __align__(16) ushort_t hbuf[4][2][16 * 40];
  const int wv = threadIdx.x >> 6;
  const int lane = threadIdx.x & 63;
  const int q = lane >> 4, nl = lane & 15;
  const int job = blockIdx.x * 4 + wv;
  const int dir = job & 1, btile = job >> 1;
  const int row0 = btile * 16 + q * 4;

  const uint4* wfL0 = wf + dir * 36 * 64;
  short8 wg4[4], wc4[2], wgh[4], wch[2];
#pragma unroll
  for (int tn = 0; tn < 4; ++tn) {
    wg4[tn] = __builtin_bit_cast(short8, wfL0[(16 + tn) * 64 + lane]);
    wgh[tn] = __builtin_bit_cast(short8, wfL0[(30 + tn) * 64 + lane]);
  }
#pragma unroll
  for (int tn = 0; tn < 2; ++tn) {
    wc4[tn] = __builtin_bit_cast(short8, wfL0[(28 + tn) * 64 + lane]);
    wch[tn] = __builtin_bit_cast(short8, wfL0[(34 + tn) * 64 + lane]);
  }
  const float* projd = proj + (size_t)dir * 5008 * 96;
  const uint4 holef4 = *reinterpret_cast<const uint4*>(cvt + U_HOLE + 128 + q * 8);

  f32x4 hc0 = {0.f, 0.f, 0.f, 0.f}, hc1 = {0.f, 0.f, 0.f, 0.f};
  short8 hA = {0, 0, 0, 0, 0, 0, 0, 0};
  ushort_t* hb0 = hbuf[wv][0];
  ushort_t* hb1 = hbuf[wv][1];

  // --- tid helper (inlined twice below via macro) ---
#define LOAD_TID(tt, dst)                                          \
  do {                                                             \
    const int _t = (tt);                                           \
    if (_t == 10) { dst[0] = dst[1] = dst[2] = dst[3] = 5000; }    \
    else {                                                         \
      const int* _tk = (_t < 10) ? tok_b : tok_a;                  \
      const int _ts = (_t < 10) ? _t : _t - 11;                    \
      _Pragma("unroll")                                            \
      for (int _r = 0; _r < 4; ++_r)                               \
        dst[_r] = _tk[(row0 + _r) * 10 + _ts];                     \
    }                                                              \
  } while (0)

#define GATHER_ACC(tid, acc)                                       \
  do {                                                             \
    _Pragma("unroll")                                              \
    for (int _g = 0; _g < 6; ++_g) {                               \
      _Pragma("unroll")                                            \
      for (int _r = 0; _r < 4; ++_r)                               \
        acc[_g][_r] = projd[((size_t)tid[_r] * 6 + _g) * 16 + nl]; \
    }                                                              \
  } while (0)

#define LOAD_AF4(tt, dst)                                                         \
  do {                                                                            \
    const int _t = (tt);                                                          \
    if (_t == 10) dst = __builtin_bit_cast(short8, holef4);                       \
    else {                                                                        \
      const int _side = (_t < 10) ? 0 : 1;                                        \
      const int _ts = (_t < 10) ? _t : _t - 11;                                   \
      dst = __builtin_bit_cast(short8,                                            \
          typf[((size_t)(_side * 10 + _ts) * 512 + btile) * 64 + lane]);          \
    }                                                                             \
  } while (0)

  int tidN[4], tidN2[4];
  f32x4 px[6];
  {
    const int t0 = dir ? 20 : 0;
    int tidC[4];
    f32x4 accC[6];
    short8 af4;
    LOAD_TID(t0, tidC);
    GATHER_ACC(tidC, accC);
    LOAD_AF4(t0, af4);
    LOAD_TID(dir ? 19 : 1, tidN);
#pragma unroll
    for (int tn = 0; tn < 4; ++tn) px[tn] = mfma16(af4, wg4[tn], accC[tn]);
#pragma unroll
    for (int tn = 0; tn < 2; ++tn) px[4 + tn] = mfma16(af4, wc4[tn], accC[4 + tn]);
  }

  for (int s = 0; s < 21; ++s) {
    const int t = dir ? 20 - s : s;

    f32x4 accN[6];
    short8 af4n;
    if (s < 20) {
      GATHER_ACC(tidN, accN);
      LOAD_AF4(dir ? t - 1 : t + 1, af4n);
    }
    if (s < 19) LOAD_TID(dir ? t - 2 : t + 2, tidN2);

    // ---- critical path ----
    f32x4 ru[4];
#pragma unroll
    for (int tn = 0; tn < 4; ++tn) ru[tn] = mfma16(hA, wgh[tn], px[tn]);
#pragma unroll
    for (int tn = 0; tn < 4; ++tn)
#pragma unroll
      for (int r = 0; r < 4; ++r) ru[tn][r] = sgm(ru[tn][r]);

#pragma unroll
    for (int r = 0; r < 4; ++r) {
      hb0[(q * 4 + r) * 40 + nl]      = f2bf(ru[0][r] * hc0[r]);
      hb0[(q * 4 + r) * 40 + 16 + nl] = f2bf(ru[1][r] * hc1[r]);
    }
    short8 rhA = *reinterpret_cast<const short8*>(hb0 + nl * 40 + q * 8);

    f32x4 cc0 = mfma16(rhA, wch[0], px[4]);
    f32x4 cc1 = mfma16(rhA, wch[1], px[5]);
#pragma unroll
    for (int r = 0; r < 4; ++r) {
      const float c0 = tnh(cc0[r]), c1 = tnh(cc1[r]);
      const float u0 = ru[2][r], u1 = ru[3][r];
      hc0[r] = u0 * hc0[r] + (1.f - u0) * c0;
      hc1[r] = u1 * hc1[r] + (1.f - u1) * c1;
    }

#pragma unroll
    for (int r = 0; r < 4; ++r) {
      hb1[(q * 4 + r) * 40 + nl]      = f2bf(hc0[r]);
      hb1[(q * 4 + r) * 40 + 16 + nl] = f2bf(hc1[r]);
    }
    hA = *reinterpret_cast<const short8*>(hb1 + nl * 40 + q * 8);
    y0a[((size_t)(t * 512 + btile) * 2 + dir) * 64 + lane] = __builtin_bit_cast(uint4, hA);

    // ---- pipeline: build next step's x-partial ----
    if (s < 20) {
#pragma unroll
      for (int tn = 0; tn < 4; ++tn) px[tn] = mfma16(af4n, wg4[tn], accN[tn]);
#pragma unroll
      for (int tn = 0; tn < 2; ++tn) px[4 + tn] = mfma16(af4n, wc4[tn], accN[4 + tn]);
#pragma unroll
      for (int r = 0; r < 4; ++r) tidN[r] = tidN2[r];
    }
  }
#undef LOAD_TID
#undef GATHER_ACC
#undef LOAD_AF4
}

// ---------------------------------------------------------------------------
// k3b: layer-1 recurrence; 16 y-MFMAs pipelined to previous step, 6 h-MFMAs
// on critical path. FP32 output [b][21][64].
// ---------------------------------------------------------------------------
__global__ __launch_bounds__(256, 1) void k3b(
    const ushort_t* __restrict__ cvt, const uint4* __restrict__ wf,
    const uint4* __restrict__ y0a, float* __restrict__ out) {
  __shared__ __align__(16) ushort_t hbuf[4][2][16 * 40];
  const int wv = threadIdx.x >> 6;
  const int lane = threadIdx.x & 63;
  const int q = lane >> 4, nl = lane & 15;
  const int job = blockIdx.x * 4 + wv;
  const int dir = job & 1, btile = job >> 1;

  const uint4* wfL1 = wf + (72 + dir * 18) * 64;
  short8 wgx0[4], wgx1[4], wgh[4], wcx0[2], wcx1[2], wch[2];
#pragma unroll
  for (int tn = 0; tn < 4; ++tn) {
    wgx0[tn] = __builtin_bit_cast(short8, wfL1[tn * 64 + lane]);
    wgx1[tn] = __builtin_bit_cast(short8, wfL1[(4 + tn) * 64 + lane]);
    wgh[tn]  = __builtin_bit_cast(short8, wfL1[(8 + tn) * 64 + lane]);
  }
#pragma unroll
  for (int tn = 0; tn < 2; ++tn) {
    wcx0[tn] = __builtin_bit_cast(short8, wfL1[(12 + tn) * 64 + lane]);
    wcx1[tn] = __builtin_bit_cast(short8, wfL1[(14 + tn) * 64 + lane]);
    wch[tn]  = __builtin_bit_cast(short8, wfL1[(16 + tn) * 64 + lane]);
  }
  const ushort_t* gb = cvt + (dir ? U_GBBW1 : U_GBFW1);
  const ushort_t* cb = cvt + (dir ? U_CBBW1 : U_CBFW1);
  float gb4[4], cb4[2];
#pragma unroll
  for (int tn = 0; tn < 4; ++tn) gb4[tn] = bf2f((unsigned)gb[tn * 16 + nl]);
#pragma unroll
  for (int tn = 0; tn < 2; ++tn) cb4[tn] = bf2f((unsigned)cb[tn * 16 + nl]);

  f32x4 hc0 = {0.f, 0.f, 0.f, 0.f}, hc1 = {0.f, 0.f, 0.f, 0.f};
  short8 hA = {0, 0, 0, 0, 0, 0, 0, 0};
  ushort_t* hb0 = hbuf[wv][0];
  ushort_t* hb1 = hbuf[wv][1];

  f32x4 px[6];
  {
    const int t0 = dir ? 20 : 0;
    const short8 ya0 = __builtin_bit_cast(short8, y0a[((size_t)(t0 * 512 + btile) * 2 + 0) * 64 + lane]);
    const short8 ya1 = __builtin_bit_cast(short8, y0a[((size_t)(t0 * 512 + btile) * 2 + 1) * 64 + lane]);
#pragma unroll
    for (int tn = 0; tn < 4; ++tn) {
      f32x4 acc = {gb4[tn], gb4[tn], gb4[tn], gb4[tn]};
      acc = mfma16(ya0, wgx0[tn], acc);
      acc = mfma16(ya1, wgx1[tn], acc);
      px[tn] = acc;
    }
#pragma unroll
    for (int tn = 0; tn < 2; ++tn) {
      f32x4 acc = {cb4[tn], cb4[tn], cb4[tn], cb4[tn]};
      acc = mfma16(ya0, wcx0[tn], acc);
      acc = mfma16(ya1, wcx1[tn], acc);
      px[4 + tn] = acc;
    }
  }

  for (int s = 0; s < 21; ++s) {
    const int t = dir ? 20 - s : s;

    short8 yn0, yn1;
    if (s < 20) {
      const int t2 = dir ? t - 1 : t + 1;
      yn0 = __builtin_bit_cast(short8, y0a[((size_t)(t2 * 512 + btile) * 2 + 0) * 64 + lane]);
      yn1 = __builtin_bit_cast(short8, y0a[((size_t)(t2 * 512 + btile) * 2 + 1) * 64 + lane]);
    }

    // ---- critical path ----
    f32x4 ru[4];
#pragma unroll
    for (int tn = 0; tn < 4; ++tn) ru[tn] = mfma16(hA, wgh[tn], px[tn]);
#pragma unroll
    for (int tn = 0; tn < 4; ++tn)
#pragma unroll
      for (int r = 0; r < 4; ++r) ru[tn][r] = sgm(ru[tn][r]);

#pragma unroll
    for (int r = 0; r < 4; ++r) {
      hb0[(q * 4 + r) * 40 + nl]      = f2bf(ru[0][r] * hc0[r]);
      hb0[(q * 4 + r) * 40 + 16 + nl] = f2bf(ru[1][r] * hc1[r]);
    }
    short8 rhA = *reinterpret_cast<const short8*>(hb0 + nl * 40 + q * 8);

    f32x4 cc0 = mfma16(rhA, wch[0], px[4]);
    f32x4 cc1 = mfma16(rhA, wch[1], px[5]);
#pragma unroll
    for (int r = 0; r < 4; ++r) {
      const float c0 = tnh(cc0[r]), c1 = tnh(cc1[r]);
      const float u0 = ru[2][r], u1 = ru[3][r];
      hc0[r] = u0 * hc0[r] + (1.f - u0) * c0;
      hc1[r] = u1 * hc1[r] + (1.f - u1) * c1;
    }

#pragma unroll
    for (int r = 0; r < 4; ++r) {
      hb1[(q * 4 + r) * 40 + nl]      = f2bf(hc0[r]);
      hb1[(q * 4 + r) * 40 + 16 + nl] = f2bf(hc1[r]);
    }
    hA = *reinterpret_cast<const short8*>(hb1 + nl * 40 + q * 8);

#pragma unroll
    for (int r = 0; r < 4; ++r) {
      const size_t o = ((size_t)(btile * 16 + q * 4 + r) * 21 + t) * 64 + dir * 32 + nl;
      out[o]      = hc0[r];
      out[o + 16] = hc1[r];
    }

    // ---- pipeline: next step's y-partials ----
    if (s < 20) {
#pragma unroll
      for (int tn = 0; tn < 4; ++tn) {
        f32x4 acc = {gb4[tn], gb4[tn], gb4[tn], gb4[tn]};
        acc = mfma16(yn0, wgx0[tn], acc);
        acc = mfma16(yn1, wgx1[tn], acc);
        px[tn] = acc;
      }
#pragma unroll
      for (int tn = 0; tn < 2; ++tn) {
        f32x4 acc = {cb4[tn], cb4[tn], cb4[tn], cb4[tn]};
        acc = mfma16(yn0, wcx0[tn], acc);
        acc = mfma16(yn1, wcx1[tn], acc);
        px[4 + tn] = acc;
      }
    }
  }
}

// ---------------------------------------------------------------------------
extern "C" void kernel_launch(void* const* d_in, const int* in_sizes, int n_in,
                              void* d_out, int out_size, void* d_ws, size_t ws_size,
                              hipStream_t stream)
{
  const int* tok_b = (const int*)d_in[0];
  const void* slot_tb = d_in[1];
  const void* slot_mb = d_in[2];
  const int* tok_a = (const int*)d_in[3];
  const void* slot_ta = d_in[4];
  const void* slot_ma = d_in[5];

  int* flags = (int*)d_ws;
  ushort_t* cvt = (ushort_t*)((char*)d_ws + 64);
  uint4* y0a = (uint4*)((char*)d_ws + Y0A_OFF);
  uint4* typf = (uint4*)((char*)d_ws + TYPF_OFF);
  uint4* wf  = (uint4*)((char*)d_ws + WF_OFF);
  float* proj = (float*)((char*)d_ws + PROJ_OFF);

  k0_detect<<<dim3(1), dim3(64), 0, stream>>>(
      (const ushort_t*)d_in[6], (const unsigned*)slot_mb, (const unsigned*)slot_tb,
      flags);

  static const int slen[19] = {640000, 160000, 160,
                               12288, 64, 6144, 32, 12288, 64, 6144, 32,
                               6144, 64, 3072, 32, 6144, 64, 3072, 32};
  static const int sdst[19] = {U_TOKEMB, U_TYPEMB, U_HOLE,
                               U_GKFW0, U_GBFW0, U_CKFW0, U_CBFW0,
                               U_GKBW0, U_GBBW0, U_CKBW0, U_CBBW0,
                               U_GKFW1, U_GBFW1, U_CKFW1, U_CBFW1,
                               U_GKBW1, U_GBBW1, U_CKBW1, U_CBBW1};
  Cvt19 a;
  int tot = 0;
  for (int i = 0; i < 19; ++i) {
    a.src[i] = d_in[6 + i]; a.len[i] = slen[i]; a.dst[i] = sdst[i]; tot += slen[i];
  }
  kcvt<<<dim3((tot + 255) / 256), dim3(256), 0, stream>>>(a, cvt, flags);

  kswz<<<dim3(27), dim3(256), 0, stream>>>(cvt, wf);

  ktypmax<<<dim3(2560), dim3(256), 0, stream>>>(
      slot_tb, slot_mb, slot_ta, slot_ma, cvt, typf, flags);

  kproj<<<dim3(157), dim3(256), 0, stream>>>(cvt, wf, proj);

  krec0<<<dim3(256), dim3(256), 0, stream>>>(tok_b, tok_a, cvt, wf, typf, proj, y0a);

  k3b<<<dim3(256), dim3(256), 0, stream>>>(cvt, wf, y0a, (float*)d_out);
}